// Round 13
// baseline (31.109 us; speedup 1.0000x reference)
//
#include <hip/hip_runtime.h>
#include <math.h>

#define BIG_NEG (-1.0e9f)

constexpr int B = 16, T = 2048, D = 64, C = 32, NF = 16;

typedef float f32x4 __attribute__((ext_vector_type(4)));

// ---------------------------------------------------------------------------
// megakernel v2: chunk=32, 1024 work blocks (4/CU), xx deduped.
//  blocks 0..1023 : (b, t-chunk of 32) -> stage feat halo tile, em, local
//                   sliding-window scan, K contiguous output panels.
//  block  1024    : transition log-softmax
//  block  1025    : init_lp
// ---------------------------------------------------------------------------
template<int KT, bool EXACT>
__global__ __launch_bounds__(256) void megakernel(
    const float* __restrict__ feat,    // (B,T,D)
    const float* __restrict__ P,       // (D,NF)
    const float* __restrict__ TL,      // (C,D)
    const float* __restrict__ TR,      // (C,D)
    const float* __restrict__ STD,     // (D,)
    const float* __restrict__ MEANS,   // (C,D)
    const float* __restrict__ PLR,     // (C,)
    const float* __restrict__ LOGITS,  // (C,)
    float* __restrict__ out,           // (B,K,T,C)
    float* __restrict__ out_trans,     // (C,C)
    float* __restrict__ out_init,      // (C,)
    int Krt)
{
    constexpr int RTOT = 32 + KT;          // staged rows (halo + chunk)
    constexpr int NQ   = (RTOT + 3) / 4;   // t-quads for emission
    constexpr int RPS  = (RTOT + 7) / 8;   // rows per scan-thread

    __shared__ float fs[RTOT * 64];        // feat tile (swizzled); later S[]
    __shared__ float wm_lds[C * 68];       // means*inv_var, padded stride
    __shared__ float iv_lds[64];
    __shared__ float E[RTOT * 33];         // xm values [r][c], padded
    __shared__ float xxl[RTOT];            // xx[r] (c-independent, deduped)
    __shared__ float sllp[KT * C];         // llp_eff
    __shared__ float slncc[C];             // ln + cc[c]
    __shared__ float red[8 * 33];
    __shared__ float lgam[32];
    __shared__ float scc[C];
    __shared__ float sln;

    const int bid = blockIdx.x;
    const int tid = threadIdx.x;
    const int KRUN = EXACT ? KT : Krt;

    if (bid < 1024) {
        const int b  = bid & 15;            // XCD = b%8
        const int t0 = (bid >> 4) << 5;     // chunk * 32

        // ---- stage feat rows [t0-KT, t0+32) into fs (XOR-swizzled) ----
        const float* fb = feat + (size_t)b * T * D;
        constexpr int NF4 = RTOT * 16;
#pragma unroll
        for (int it = 0; it < (NF4 + 255) / 256; ++it) {
            const int idx4 = tid + it * 256;
            if (idx4 < NF4) {
                const int fi  = idx4 * 4;
                const int row = fi >> 6;
                const int col = fi & 63;
                const int t   = t0 - KT + row;
                f32x4 v = {0.f, 0.f, 0.f, 0.f};
                if (t >= 0) v = *(const f32x4*)(fb + (size_t)t * D + col);
                const int cswz = col ^ (((row >> 2) & 7) << 2);
                *(f32x4*)(fs + row * 64 + cswz) = v;
            }
        }
        // ---- stage wm = MEANS * iv, and iv ----
#pragma unroll
        for (int it = 0; it < 2; ++it) {
            const int idx = tid * 4 + it * 1024;
            const int c = idx >> 6, d = idx & 63;
            const f32x4 m = *(const f32x4*)(MEANS + idx);
            const f32x4 s = *(const f32x4*)(STD + d);
            f32x4 w = {m.x / (s.x * s.x), m.y / (s.y * s.y),
                       m.z / (s.z * s.z), m.w / (s.w * s.w)};
            *(f32x4*)(wm_lds + c * 68 + d) = w;
        }
        if (tid < 16) {
            const f32x4 s = *(const f32x4*)(STD + tid * 4);
            f32x4 v = {1.f / (s.x * s.x), 1.f / (s.y * s.y),
                       1.f / (s.z * s.z), 1.f / (s.w * s.w)};
            *(f32x4*)(iv_lds + tid * 4) = v;
        }
        // ---- scalar tables: lgam (wave0), ln (wave1), cc (wave3) ----
        if (tid < 32) {
            float x = (tid >= 1) ? logf((float)(tid + 1)) : 0.f;
#pragma unroll
            for (int off = 1; off < 32; off <<= 1) {
                float vv = __shfl_up(x, off, 64);
                if (tid >= off) x += vv;
            }
            lgam[tid] = x;                 // lgamma(k+2) for k=tid
        } else if (tid >= 64 && tid < 128) {
            const int l = tid - 64;
            float lg = logf(STD[l]);
#pragma unroll
            for (int off = 1; off < 64; off <<= 1) lg += __shfl_xor(lg, off, 64);
            if (l == 0) sln = -lg - 58.81206612510332f;
        } else if (tid >= 192 && tid < 224) {
            const int c = tid - 192;
            float acc = 0.f;
#pragma unroll
            for (int dq = 0; dq < 64; dq += 4) {
                const f32x4 m = *(const f32x4*)(MEANS + c * 64 + dq);
                const f32x4 s = *(const f32x4*)(STD + dq);
                acc += (m.x * m.x) / (s.x * s.x) + (m.y * m.y) / (s.y * s.y)
                     + (m.z * m.z) / (s.z * s.z) + (m.w * m.w) / (s.w * s.w);
            }
            scc[c] = -0.5f * acc;
        }
        __syncthreads();

        // ---- emission xm into E: thread (i = t-quad, j = c-pair) ----
        {
            const int i = tid & 15, j = tid >> 4;
            if (i < NQ) {
                const int swz = (i & 7) << 2;
                const float* wr0 = wm_lds + (2 * j) * 68;
                const float* wr1 = wr0 + 68;
                float a0[4] = {0,0,0,0}, a1[4] = {0,0,0,0};
#pragma unroll
                for (int q = 0; q < 16; ++q) {
                    const int dq = q * 4;
                    const f32x4 w0 = *(const f32x4*)(wr0 + dq);
                    const f32x4 w1 = *(const f32x4*)(wr1 + dq);
                    const int cswz = dq ^ swz;
#pragma unroll
                    for (int tt = 0; tt < 4; ++tt) {
                        const f32x4 f = *(const f32x4*)(fs + (4*i+tt)*64 + cswz);
                        a0[tt] = fmaf(f.x, w0.x, a0[tt]); a0[tt] = fmaf(f.y, w0.y, a0[tt]);
                        a0[tt] = fmaf(f.z, w0.z, a0[tt]); a0[tt] = fmaf(f.w, w0.w, a0[tt]);
                        a1[tt] = fmaf(f.x, w1.x, a1[tt]); a1[tt] = fmaf(f.y, w1.y, a1[tt]);
                        a1[tt] = fmaf(f.z, w1.z, a1[tt]); a1[tt] = fmaf(f.w, w1.w, a1[tt]);
                    }
                }
#pragma unroll
                for (int tt = 0; tt < 4; ++tt) {
                    E[(4*i+tt) * 33 + 2*j]     = a0[tt];
                    E[(4*i+tt) * 33 + 2*j + 1] = a1[tt];
                }
            }
        }
        // ---- xx[r] once per row (deduped) ----
        if (tid < RTOT) {
            const int row = tid;
            const int swz = ((row >> 2) & 7) << 2;
            float xx = 0.f;
#pragma unroll
            for (int q = 0; q < 16; ++q) {
                const int dq = q * 4;
                const f32x4 f   = *(const f32x4*)(fs + row * 64 + (dq ^ swz));
                const f32x4 iv4 = *(const f32x4*)(iv_lds + dq);
                xx = fmaf(f.x * iv4.x, f.x, xx);
                xx = fmaf(f.y * iv4.y, f.y, xx);
                xx = fmaf(f.z * iv4.z, f.z, xx);
                xx = fmaf(f.w * iv4.w, f.w, xx);
            }
            xxl[row] = xx;
        }
        // ---- llp_eff + lncc ----
        if (tid < C) slncc[tid] = sln + scc[tid];
        for (int e = tid; e < KRUN * C; e += 256) {
            const int k = e >> 5, c = e & 31;
            const float plr = PLR[c];
            sllp[e] = (float)(k + 1) * (plr + sln + scc[c]) - expf(plr) - lgam[k];
        }
        __syncthreads();

        // ---- LOCAL scan of (E - 0.5*xx) -> S in fs ----
        {
            const int c = tid & 31, s = tid >> 5;
            float incl[RPS];
            float run = 0.f;
#pragma unroll
            for (int q = 0; q < RPS; ++q) {
                const int r = s * RPS + q;
                const float v = (r < RTOT) ? (E[r * 33 + c] - 0.5f * xxl[r]) : 0.f;
                run += v;
                incl[q] = run;
            }
            red[s * 33 + c] = run;
            __syncthreads();
            float off = 0.f;
#pragma unroll
            for (int s2 = 0; s2 < 7; ++s2) off += (s2 < s) ? red[s2 * 33 + c] : 0.f;
            float* S = fs;                       // reuse (feat no longer needed)
            if (s == 0) S[c] = 0.f;
#pragma unroll
            for (int q = 0; q < RPS; ++q) {
                const int r = s * RPS + q;
                if (r < RTOT) S[(r + 1) * 32 + c] = off + incl[q];
            }
        }
        __syncthreads();

        // ---- span compute + contiguous panel stores ----
        const float* S = fs;
        const int c4 = (tid & 7) << 2;
        const int tb = tid >> 3;                 // 0..31
        const int ja = tb + KT;
        const int ta = t0 + tb;

        const f32x4 ea  = *(const f32x4*)&S[(ja + 1) * 32 + c4];
        const f32x4 ln4 = *(const f32x4*)&slncc[c4];

        float* ob = out + ((size_t)(b * KRUN) * T + t0) * C + c4;
#pragma unroll
        for (int k = 0; k < KRUN; ++k) {         // fully unrolls when EXACT
            const f32x4 lv = *(const f32x4*)&sllp[k * 32 + c4];
            const f32x4 sa = *(const f32x4*)&S[(ja - k) * 32 + c4];
            const f32x4 mk = BIG_NEG - (float)(k + 1) * ln4;
            f32x4 ra = ea - sa + lv;
            if (ta < k) ra = mk + lv;
            *(f32x4*)(ob + (size_t)k * T * C + tb * C) = ra;
        }

    } else if (bid == 1024) {
        // ---------------- transition log-softmax (reuses fs) ----------------
        float* left  = fs;            // C*NF
        float* right = fs + 512;      // C*NF
        float* M     = fs + 1024;     // C*(C+1)
        float* lse   = fs + 2112;     // C
        for (int e = tid; e < C * NF; e += 256) {
            int cc = e >> 4, f = e & (NF - 1);
            float aL = 0.f, aR = 0.f;
            for (int d = 0; d < D; ++d) {
                float p = P[d * NF + f];
                aL = fmaf(TL[cc * D + d], p, aL);
                aR = fmaf(TR[cc * D + d], p, aR);
            }
            left[cc * NF + f] = aL;
            right[cc * NF + f] = aR;
        }
        __syncthreads();
        for (int e = tid; e < C * C; e += 256) {
            int i = e >> 5, jj = e & 31;
            float acc = 0.f;
            for (int f = 0; f < NF; ++f)
                acc = fmaf(right[i * NF + f], left[jj * NF + f], acc);
            M[i * 33 + jj] = acc;
        }
        __syncthreads();
        if (tid < C) {
            float mx = -INFINITY;
            for (int i = 0; i < C; ++i) mx = fmaxf(mx, M[i * 33 + tid]);
            float s = 0.f;
            for (int i = 0; i < C; ++i) s += expf(M[i * 33 + tid] - mx);
            lse[tid] = logf(s) + mx;
        }
        __syncthreads();
        for (int e = tid; e < C * C; e += 256)
            out_trans[e] = M[(e >> 5) * 33 + (e & 31)] - lse[e & 31];

    } else {
        // ---------------- init_lp ----------------
        if (tid < 32) {
            float vv = LOGITS[tid];
            float mx = vv;
#pragma unroll
            for (int off = 1; off < 32; off <<= 1)
                mx = fmaxf(mx, __shfl_xor(mx, off, 64));
            float s = expf(vv - mx);
#pragma unroll
            for (int off = 1; off < 32; off <<= 1) s += __shfl_xor(s, off, 64);
            out_init[tid] = vv - mx - logf(s);
        }
    }
}

// ---------------------------------------------------------------------------
extern "C" void kernel_launch(void* const* d_in, const int* in_sizes, int n_in,
                              void* d_out, int out_size, void* d_ws, size_t ws_size,
                              hipStream_t stream) {
    const float* feat   = (const float*)d_in[0];
    const float* P      = (const float*)d_in[1];
    const float* TL     = (const float*)d_in[2];
    const float* TR     = (const float*)d_in[3];
    const float* MEANS  = (const float*)d_in[4];
    const float* STDV   = (const float*)d_in[5];
    const float* PLR    = (const float*)d_in[6];
    const float* LOGITS = (const float*)d_in[7];

    const int K = (out_size - (C * C + C)) / (B * T * C);

    float* out       = (float*)d_out;
    float* out_trans = out + (size_t)B * K * T * C;
    float* out_init  = out_trans + C * C;

    if (K == 20) {
        megakernel<20, true><<<1026, 256, 0, stream>>>(
            feat, P, TL, TR, STDV, MEANS, PLR, LOGITS,
            out, out_trans, out_init, K);
    } else if (K == 16) {
        megakernel<16, true><<<1026, 256, 0, stream>>>(
            feat, P, TL, TR, STDV, MEANS, PLR, LOGITS,
            out, out_trans, out_init, K);
    } else if (K == 24) {
        megakernel<24, true><<<1026, 256, 0, stream>>>(
            feat, P, TL, TR, STDV, MEANS, PLR, LOGITS,
            out, out_trans, out_init, K);
    } else {
        megakernel<32, false><<<1026, 256, 0, stream>>>(
            feat, P, TL, TR, STDV, MEANS, PLR, LOGITS,
            out, out_trans, out_init, K);
    }
}

// Round 14
// 25.929 us; speedup vs baseline: 1.1998x; 1.1998x over previous
//
#include <hip/hip_runtime.h>
#include <math.h>

#define BIG_NEG (-1.0e9f)

constexpr int B = 16, T = 2048, D = 64, C = 32, NF = 16;

typedef float f32x4 __attribute__((ext_vector_type(4)));
using bf16x8 = __attribute__((ext_vector_type(8))) short;

__device__ inline ushort f2bf(float x) {
    union { float f; unsigned u; } cv; cv.f = x;
    unsigned u = cv.u;
    u += 0x7FFF + ((u >> 16) & 1);          // RNE
    return (ushort)(u >> 16);
}

// ---------------------------------------------------------------------------
// megakernel v3: chunk 64, cumsum-first + bf16 MFMA for S = csF*wm^T.
//  blocks 0..511 : stage feat halo -> csF (bf16) + csxx (f32) -> MFMA -> span
//  block  512    : transition log-softmax
//  block  513    : init_lp
// em folded: S_em[r] = Sm[r] - 0.5*csxx[r]; log_norm+cc folded into llp_eff;
// masked entries: BIG_NEG - (k+1)*lncc[c] + llp_eff.
// ---------------------------------------------------------------------------
template<int KT, bool EXACT>
__global__ __launch_bounds__(256) void megakernel(
    const float* __restrict__ feat,    // (B,T,D)
    const float* __restrict__ P,       // (D,NF)
    const float* __restrict__ TL,      // (C,D)
    const float* __restrict__ TR,      // (C,D)
    const float* __restrict__ STD,     // (D,)
    const float* __restrict__ MEANS,   // (C,D)
    const float* __restrict__ PLR,     // (C,)
    const float* __restrict__ LOGITS,  // (C,)
    float* __restrict__ out,           // (B,K,T,C)
    float* __restrict__ out_trans,     // (C,C)
    float* __restrict__ out_init,      // (C,)
    int Krt)
{
    constexpr int RTOT = 64 + KT;           // em rows (halo + chunk)
    constexpr int ROWS = RTOT + 1;          // prefix rows
    constexpr int NT   = (ROWS + 15) / 16;  // 16-row MFMA tiles
    constexpr int CR   = RTOT / 4;          // cumsum rows per thread
    constexpr int XSEG = (RTOT + 7) / 8;    // csxx segment length

    // --- smem carve (f32 units) ---
    constexpr int OFF_FS   = 0;                          // RTOT*64 (S overlays)
    constexpr int OFF_CSBF = OFF_FS + RTOT * 64;         // NT*16*32 (ushort buf)
    constexpr int OFF_WMBF = OFF_CSBF + NT * 16 * 32;    // 1152 (32*72 ushort)
    constexpr int OFF_XX   = OFF_WMBF + 1152;            // RTOT
    constexpr int OFF_CSXX = OFF_XX + RTOT;              // ROWS
    constexpr int OFF_RED  = (OFF_CSXX + ROWS + 3) & ~3; // 256
    constexpr int OFF_RED2 = OFF_RED + 256;              // 8
    constexpr int OFF_LLP  = OFF_RED2 + 8;               // KT*32
    constexpr int OFF_LNCC = OFF_LLP + KT * 32;          // 32
    constexpr int OFF_LGAM = OFF_LNCC + 32;              // 32
    constexpr int OFF_SCC  = OFF_LGAM + 32;              // 32
    constexpr int OFF_SLN  = OFF_SCC + 32;               // 4
    constexpr int OFF_IV   = OFF_SLN + 4;                // 64
    constexpr int SMEM_F32 = OFF_IV + 64;
    __shared__ float smem[SMEM_F32];

    float*  fs    = smem + OFF_FS;
    float*  S     = smem + OFF_FS;          // overlay (fs dead after P1)
    ushort* csbf  = (ushort*)(smem + OFF_CSBF);
    ushort* wmb   = (ushort*)(smem + OFF_WMBF);
    float*  xxl   = smem + OFF_XX;
    float*  csxx  = smem + OFF_CSXX;
    float*  red   = smem + OFF_RED;
    float*  red2  = smem + OFF_RED2;
    float*  sllp  = smem + OFF_LLP;
    float*  slncc = smem + OFF_LNCC;
    float*  lgam  = smem + OFF_LGAM;
    float*  scc   = smem + OFF_SCC;
    float*  slnp  = smem + OFF_SLN;
    float*  ivp   = smem + OFF_IV;

    const int bid = blockIdx.x;
    const int tid = threadIdx.x;
    const int KRUN = EXACT ? KT : Krt;

    if (bid < 512) {
        const int b  = bid & 15;            // XCD = b%8
        const int t0 = (bid >> 4) << 6;     // chunk * 64

        // =================== P0: staging ===================
        const float* fb = feat + (size_t)b * T * D;
        constexpr int NF4 = RTOT * 16;
#pragma unroll
        for (int it = 0; it < (NF4 + 255) / 256; ++it) {
            const int idx4 = tid + it * 256;
            if (idx4 < NF4) {
                const int fi  = idx4 * 4;
                const int row = fi >> 6;
                const int col = fi & 63;
                const int t   = t0 - KT + row;
                f32x4 v = {0.f, 0.f, 0.f, 0.f};
                if (t >= 0) v = *(const f32x4*)(fb + (size_t)t * D + col);
                const int cswz = col ^ (((row >> 2) & 7) << 2);
                *(f32x4*)(fs + row * 64 + cswz) = v;
            }
        }
        // wm bf16 [c][72]
#pragma unroll
        for (int it = 0; it < 2; ++it) {
            const int idx = (tid + it * 256) * 4;
            const int c = idx >> 6, d = idx & 63;
            const f32x4 m = *(const f32x4*)(MEANS + idx);
            const f32x4 s = *(const f32x4*)(STD + d);
            ushort4 u;
            u.x = f2bf(m.x / (s.x * s.x));
            u.y = f2bf(m.y / (s.y * s.y));
            u.z = f2bf(m.z / (s.z * s.z));
            u.w = f2bf(m.w / (s.w * s.w));
            *(ushort4*)(wmb + c * 72 + d) = u;
        }
        if (tid < 16) {
            const f32x4 s = *(const f32x4*)(STD + tid * 4);
            f32x4 v = {1.f / (s.x * s.x), 1.f / (s.y * s.y),
                       1.f / (s.z * s.z), 1.f / (s.w * s.w)};
            *(f32x4*)(ivp + tid * 4) = v;
        }
        // tables
        if (tid < 32) {
            float x = (tid >= 1) ? logf((float)(tid + 1)) : 0.f;
#pragma unroll
            for (int off = 1; off < 32; off <<= 1) {
                float vv = __shfl_up(x, off, 64);
                if (tid >= off) x += vv;
            }
            lgam[tid] = x;                 // lgamma(k+2)
        } else if (tid >= 64 && tid < 128) {
            const int l = tid - 64;
            float lg = logf(STD[l]);
#pragma unroll
            for (int off = 1; off < 64; off <<= 1) lg += __shfl_xor(lg, off, 64);
            if (l == 0) *slnp = -lg - 58.81206612510332f;
        } else if (tid >= 192 && tid < 224) {
            const int c = tid - 192;
            float acc = 0.f;
#pragma unroll
            for (int dq = 0; dq < 64; dq += 4) {
                const f32x4 m = *(const f32x4*)(MEANS + c * 64 + dq);
                const f32x4 s = *(const f32x4*)(STD + dq);
                acc += (m.x * m.x) / (s.x * s.x) + (m.y * m.y) / (s.y * s.y)
                     + (m.z * m.z) / (s.z * s.z) + (m.w * m.w) / (s.w * s.w);
            }
            scc[c] = -0.5f * acc;
        }
        __syncthreads();

        // =================== P1: cumsum pass1 + xx + sllp ===================
        const int col = tid & 63, seg = tid >> 6;
        float loc[CR];
        {
            float runp = 0.f;
#pragma unroll
            for (int q = 0; q < CR; ++q) {
                const int row = seg * CR + q;
                const float v = fs[row * 64 + (col ^ (((row >> 2) & 7) << 2))];
                loc[q] = v;
                runp += v;
            }
            red[seg * 64 + col] = runp;
        }
        if (tid < RTOT) {
            const int row = tid;
            const int swz = ((row >> 2) & 7) << 2;
            float xx = 0.f;
#pragma unroll
            for (int q = 0; q < 16; ++q) {
                const int dq = q * 4;
                const f32x4 f   = *(const f32x4*)(fs + row * 64 + (dq ^ swz));
                const f32x4 iv4 = *(const f32x4*)(ivp + dq);
                xx = fmaf(f.x * iv4.x, f.x, xx);
                xx = fmaf(f.y * iv4.y, f.y, xx);
                xx = fmaf(f.z * iv4.z, f.z, xx);
                xx = fmaf(f.w * iv4.w, f.w, xx);
            }
            xxl[row] = xx;
        }
        {
            const float ln = *slnp;
            if (tid < C) slncc[tid] = ln + scc[tid];
            for (int e = tid; e < KRUN * C; e += 256) {
                const int k = e >> 5, c = e & 31;
                const float plr = PLR[c];
                sllp[e] = (float)(k + 1) * (plr + ln + scc[c]) - expf(plr) - lgam[k];
            }
        }
        __syncthreads();

        // =================== P2: cumsum pass2 -> csbf; csxx pass1 ============
        {
            float off = 0.f;
#pragma unroll
            for (int s2 = 0; s2 < 3; ++s2) off += (s2 < seg) ? red[s2 * 64 + col] : 0.f;
            float run = off;
#pragma unroll
            for (int q = 0; q < CR; ++q) {
                const int row = seg * CR + q;
                csbf[row * 64 + (((col >> 3) ^ (row & 7)) << 3) + (col & 7)] = f2bf(run);
                run += loc[q];
            }
            if (seg == 3)
                csbf[RTOT * 64 + (((col >> 3) ^ (RTOT & 7)) << 3) + (col & 7)] = f2bf(run);
        }
        if (tid < 8) {
            float r2 = 0.f;
            for (int q = 0; q < XSEG; ++q) {
                const int i = tid * XSEG + q;
                if (i < RTOT) { csxx[i] = r2; r2 += xxl[i]; }
            }
            red2[tid] = r2;
        }
        __syncthreads();

        // =================== P3: csxx finalize + MFMA ===================
        if (tid < ROWS) {
            const int r = tid;
            if (r == RTOT) {
                float t = 0.f;
#pragma unroll
                for (int s2 = 0; s2 < 8; ++s2) t += red2[s2];
                csxx[r] = t;
            } else {
                const int sg = r / XSEG;
                float o = 0.f;
#pragma unroll
                for (int s2 = 0; s2 < 8; ++s2) o += (s2 < sg) ? red2[s2] : 0.f;
                csxx[r] = csxx[r] + o;
            }
        }
        {
            const int l = tid & 63, wid = tid >> 6;
            bf16x8 bfr[2][2];
#pragma unroll
            for (int ct = 0; ct < 2; ++ct)
#pragma unroll
                for (int h = 0; h < 2; ++h) {
                    const int c  = ct * 16 + (l & 15);
                    const int k0 = h * 32 + (l >> 4) * 8;
                    bfr[ct][h] = *(const bf16x8*)(wmb + c * 72 + k0);
                }
            for (int j = wid; j < NT * 2; j += 4) {
                const int rt = j >> 1, ct = j & 1;
                const int arow = rt * 16 + (l & 15);
                const int kb = l >> 4;
                const bf16x8 a0 = *(const bf16x8*)(csbf + arow * 64 + ((kb ^ (arow & 7)) << 3));
                const bf16x8 a1 = *(const bf16x8*)(csbf + arow * 64 + (((4 + kb) ^ (arow & 7)) << 3));
                f32x4 acc = {0.f, 0.f, 0.f, 0.f};
                acc = __builtin_amdgcn_mfma_f32_16x16x32_bf16(a0, bfr[ct][0], acc, 0, 0, 0);
                acc = __builtin_amdgcn_mfma_f32_16x16x32_bf16(a1, bfr[ct][1], acc, 0, 0, 0);
                const int r0  = rt * 16 + (l >> 4) * 4;
                const int cc0 = ct * 16 + (l & 15);
#pragma unroll
                for (int reg = 0; reg < 4; ++reg) {
                    const int r = r0 + reg;
                    if (r < ROWS) S[r * 36 + cc0] = acc[reg];
                }
            }
        }
        __syncthreads();

        // =================== P4: span compute + stores ===================
        const int c4 = (tid & 7) << 2;
        const int tb = tid >> 3;                 // 0..31
        const int ja = tb + KT;
        const int jb = ja + 32;
        const int ta = t0 + tb;
        const int tbg = t0 + 32 + tb;

        const f32x4 ea  = *(const f32x4*)&S[(ja + 1) * 36 + c4];
        const f32x4 eb  = *(const f32x4*)&S[(jb + 1) * 36 + c4];
        const f32x4 ln4 = *(const f32x4*)&slncc[c4];
        const float xea = csxx[ja + 1];
        const float xeb = csxx[jb + 1];

        float* ob = out + ((size_t)(b * KRUN) * T + t0) * C + c4;
#pragma unroll
        for (int k = 0; k < KRUN; ++k) {
            const f32x4 lv = *(const f32x4*)&sllp[k * 32 + c4];
            const f32x4 sa = *(const f32x4*)&S[(ja - k) * 36 + c4];
            const f32x4 sb = *(const f32x4*)&S[(jb - k) * 36 + c4];
            const float dxa = xea - csxx[ja - k];
            const float dxb = xeb - csxx[jb - k];
            const f32x4 mk = BIG_NEG - (float)(k + 1) * ln4;
            f32x4 ra = ea - sa + (lv - 0.5f * dxa);
            f32x4 rb = eb - sb + (lv - 0.5f * dxb);
            if (ta < k) ra = mk + lv;
            if (tbg < k) rb = mk + lv;
            float* op = ob + (size_t)k * T * C;
            *(f32x4*)(op + tb * C) = ra;
            *(f32x4*)(op + (32 + tb) * C) = rb;
        }

    } else if (bid == 512) {
        // ---------------- transition log-softmax ----------------
        float* left  = smem;            // C*NF
        float* right = smem + 512;      // C*NF
        float* M     = smem + 1024;     // C*(C+1)
        float* lse   = smem + 2112;     // C
        for (int e = tid; e < C * NF; e += 256) {
            int cc = e >> 4, f = e & (NF - 1);
            float aL = 0.f, aR = 0.f;
            for (int d = 0; d < D; ++d) {
                float p = P[d * NF + f];
                aL = fmaf(TL[cc * D + d], p, aL);
                aR = fmaf(TR[cc * D + d], p, aR);
            }
            left[cc * NF + f] = aL;
            right[cc * NF + f] = aR;
        }
        __syncthreads();
        for (int e = tid; e < C * C; e += 256) {
            int i = e >> 5, jj = e & 31;
            float acc = 0.f;
            for (int f = 0; f < NF; ++f)
                acc = fmaf(right[i * NF + f], left[jj * NF + f], acc);
            M[i * 33 + jj] = acc;
        }
        __syncthreads();
        if (tid < C) {
            float mx = -INFINITY;
            for (int i = 0; i < C; ++i) mx = fmaxf(mx, M[i * 33 + tid]);
            float s = 0.f;
            for (int i = 0; i < C; ++i) s += expf(M[i * 33 + tid] - mx);
            lse[tid] = logf(s) + mx;
        }
        __syncthreads();
        for (int e = tid; e < C * C; e += 256)
            out_trans[e] = M[(e >> 5) * 33 + (e & 31)] - lse[e & 31];

    } else {
        // ---------------- init_lp ----------------
        if (tid < 32) {
            float vv = LOGITS[tid];
            float mx = vv;
#pragma unroll
            for (int off = 1; off < 32; off <<= 1)
                mx = fmaxf(mx, __shfl_xor(mx, off, 64));
            float s = expf(vv - mx);
#pragma unroll
            for (int off = 1; off < 32; off <<= 1) s += __shfl_xor(s, off, 64);
            out_init[tid] = vv - mx - logf(s);
        }
    }
}

// ---------------------------------------------------------------------------
extern "C" void kernel_launch(void* const* d_in, const int* in_sizes, int n_in,
                              void* d_out, int out_size, void* d_ws, size_t ws_size,
                              hipStream_t stream) {
    const float* feat   = (const float*)d_in[0];
    const float* P      = (const float*)d_in[1];
    const float* TL     = (const float*)d_in[2];
    const float* TR     = (const float*)d_in[3];
    const float* MEANS  = (const float*)d_in[4];
    const float* STDV   = (const float*)d_in[5];
    const float* PLR    = (const float*)d_in[6];
    const float* LOGITS = (const float*)d_in[7];

    const int K = (out_size - (C * C + C)) / (B * T * C);

    float* out       = (float*)d_out;
    float* out_trans = out + (size_t)B * K * T * C;
    float* out_init  = out_trans + C * C;

    if (K == 20) {
        megakernel<20, true><<<514, 256, 0, stream>>>(
            feat, P, TL, TR, STDV, MEANS, PLR, LOGITS,
            out, out_trans, out_init, K);
    } else if (K == 16) {
        megakernel<16, true><<<514, 256, 0, stream>>>(
            feat, P, TL, TR, STDV, MEANS, PLR, LOGITS,
            out, out_trans, out_init, K);
    } else if (K == 24) {
        megakernel<24, true><<<514, 256, 0, stream>>>(
            feat, P, TL, TR, STDV, MEANS, PLR, LOGITS,
            out, out_trans, out_init, K);
    } else {
        megakernel<32, false><<<514, 256, 0, stream>>>(
            feat, P, TL, TR, STDV, MEANS, PLR, LOGITS,
            out, out_trans, out_init, K);
    }
}

// Round 15
// 25.743 us; speedup vs baseline: 1.2085x; 1.0072x over previous
//
#include <hip/hip_runtime.h>
#include <math.h>

#define BIG_NEG (-1.0e9f)

constexpr int B = 16, T = 2048, D = 64, C = 32, NF = 16;

typedef float f32x4 __attribute__((ext_vector_type(4)));
using bf16x8 = __attribute__((ext_vector_type(8))) short;

__device__ inline ushort f2bf(float x) {
    union { float f; unsigned u; } cv; cv.f = x;
    unsigned u = cv.u;
    u += 0x7FFF + ((u >> 16) & 1);          // RNE
    return (ushort)(u >> 16);
}

// ---------------------------------------------------------------------------
// megakernel v4: v3 + phase-stagger. Blocks 256..511 (co-resident partners of
// 0..255 on each CU) sleep ~2.6us before starting, so their compute phase
// overlaps the partners' store phase instead of running in lockstep.
// ---------------------------------------------------------------------------
template<int KT, bool EXACT>
__global__ __launch_bounds__(256) void megakernel(
    const float* __restrict__ feat,    // (B,T,D)
    const float* __restrict__ P,       // (D,NF)
    const float* __restrict__ TL,      // (C,D)
    const float* __restrict__ TR,      // (C,D)
    const float* __restrict__ STD,     // (D,)
    const float* __restrict__ MEANS,   // (C,D)
    const float* __restrict__ PLR,     // (C,)
    const float* __restrict__ LOGITS,  // (C,)
    float* __restrict__ out,           // (B,K,T,C)
    float* __restrict__ out_trans,     // (C,C)
    float* __restrict__ out_init,      // (C,)
    int Krt)
{
    constexpr int RTOT = 64 + KT;           // em rows (halo + chunk)
    constexpr int ROWS = RTOT + 1;          // prefix rows
    constexpr int NT   = (ROWS + 15) / 16;  // 16-row MFMA tiles
    constexpr int CR   = RTOT / 4;          // cumsum rows per thread
    constexpr int XSEG = (RTOT + 7) / 8;    // csxx segment length

    // --- smem carve (f32 units) ---
    constexpr int OFF_FS   = 0;                          // RTOT*64 (S overlays)
    constexpr int OFF_CSBF = OFF_FS + RTOT * 64;         // NT*16*32 (ushort buf)
    constexpr int OFF_WMBF = OFF_CSBF + NT * 16 * 32;    // 1152 (32*72 ushort)
    constexpr int OFF_XX   = OFF_WMBF + 1152;            // RTOT
    constexpr int OFF_CSXX = OFF_XX + RTOT;              // ROWS
    constexpr int OFF_RED  = (OFF_CSXX + ROWS + 3) & ~3; // 256
    constexpr int OFF_RED2 = OFF_RED + 256;              // 8
    constexpr int OFF_LLP  = OFF_RED2 + 8;               // KT*32
    constexpr int OFF_LNCC = OFF_LLP + KT * 32;          // 32
    constexpr int OFF_LGAM = OFF_LNCC + 32;              // 32
    constexpr int OFF_SCC  = OFF_LGAM + 32;              // 32
    constexpr int OFF_SLN  = OFF_SCC + 32;               // 4
    constexpr int OFF_IV   = OFF_SLN + 4;                // 64
    constexpr int SMEM_F32 = OFF_IV + 64;
    __shared__ float smem[SMEM_F32];

    float*  fs    = smem + OFF_FS;
    float*  S     = smem + OFF_FS;          // overlay (fs dead after P1)
    ushort* csbf  = (ushort*)(smem + OFF_CSBF);
    ushort* wmb   = (ushort*)(smem + OFF_WMBF);
    float*  xxl   = smem + OFF_XX;
    float*  csxx  = smem + OFF_CSXX;
    float*  red   = smem + OFF_RED;
    float*  red2  = smem + OFF_RED2;
    float*  sllp  = smem + OFF_LLP;
    float*  slncc = smem + OFF_LNCC;
    float*  lgam  = smem + OFF_LGAM;
    float*  scc   = smem + OFF_SCC;
    float*  slnp  = smem + OFF_SLN;
    float*  ivp   = smem + OFF_IV;

    const int bid = blockIdx.x;
    const int tid = threadIdx.x;
    const int KRUN = EXACT ? KT : Krt;

    if (bid < 512) {
        // ---- phase stagger: second dispatch round sleeps ~2.6us so its
        // compute overlaps the first round's store phase (same CU) ----
        if (bid >= 256) {
#pragma unroll
            for (int sl = 0; sl < 2; ++sl) __builtin_amdgcn_s_sleep(48);
        }

        const int b  = bid & 15;            // XCD = b%8
        const int t0 = (bid >> 4) << 6;     // chunk * 64

        // =================== P0: staging ===================
        const float* fb = feat + (size_t)b * T * D;
        constexpr int NF4 = RTOT * 16;
#pragma unroll
        for (int it = 0; it < (NF4 + 255) / 256; ++it) {
            const int idx4 = tid + it * 256;
            if (idx4 < NF4) {
                const int fi  = idx4 * 4;
                const int row = fi >> 6;
                const int col = fi & 63;
                const int t   = t0 - KT + row;
                f32x4 v = {0.f, 0.f, 0.f, 0.f};
                if (t >= 0) v = *(const f32x4*)(fb + (size_t)t * D + col);
                const int cswz = col ^ (((row >> 2) & 7) << 2);
                *(f32x4*)(fs + row * 64 + cswz) = v;
            }
        }
        // wm bf16 [c][72]
#pragma unroll
        for (int it = 0; it < 2; ++it) {
            const int idx = (tid + it * 256) * 4;
            const int c = idx >> 6, d = idx & 63;
            const f32x4 m = *(const f32x4*)(MEANS + idx);
            const f32x4 s = *(const f32x4*)(STD + d);
            ushort4 u;
            u.x = f2bf(m.x / (s.x * s.x));
            u.y = f2bf(m.y / (s.y * s.y));
            u.z = f2bf(m.z / (s.z * s.z));
            u.w = f2bf(m.w / (s.w * s.w));
            *(ushort4*)(wmb + c * 72 + d) = u;
        }
        if (tid < 16) {
            const f32x4 s = *(const f32x4*)(STD + tid * 4);
            f32x4 v = {1.f / (s.x * s.x), 1.f / (s.y * s.y),
                       1.f / (s.z * s.z), 1.f / (s.w * s.w)};
            *(f32x4*)(ivp + tid * 4) = v;
        }
        // tables
        if (tid < 32) {
            float x = (tid >= 1) ? logf((float)(tid + 1)) : 0.f;
#pragma unroll
            for (int off = 1; off < 32; off <<= 1) {
                float vv = __shfl_up(x, off, 64);
                if (tid >= off) x += vv;
            }
            lgam[tid] = x;                 // lgamma(k+2)
        } else if (tid >= 64 && tid < 128) {
            const int l = tid - 64;
            float lg = logf(STD[l]);
#pragma unroll
            for (int off = 1; off < 64; off <<= 1) lg += __shfl_xor(lg, off, 64);
            if (l == 0) *slnp = -lg - 58.81206612510332f;
        } else if (tid >= 192 && tid < 224) {
            const int c = tid - 192;
            float acc = 0.f;
#pragma unroll
            for (int dq = 0; dq < 64; dq += 4) {
                const f32x4 m = *(const f32x4*)(MEANS + c * 64 + dq);
                const f32x4 s = *(const f32x4*)(STD + dq);
                acc += (m.x * m.x) / (s.x * s.x) + (m.y * m.y) / (s.y * s.y)
                     + (m.z * m.z) / (s.z * s.z) + (m.w * m.w) / (s.w * s.w);
            }
            scc[c] = -0.5f * acc;
        }
        __syncthreads();

        // =================== P1: cumsum pass1 + xx + sllp ===================
        const int col = tid & 63, seg = tid >> 6;
        float loc[CR];
        {
            float runp = 0.f;
#pragma unroll
            for (int q = 0; q < CR; ++q) {
                const int row = seg * CR + q;
                const float v = fs[row * 64 + (col ^ (((row >> 2) & 7) << 2))];
                loc[q] = v;
                runp += v;
            }
            red[seg * 64 + col] = runp;
        }
        if (tid < RTOT) {
            const int row = tid;
            const int swz = ((row >> 2) & 7) << 2;
            float xx = 0.f;
#pragma unroll
            for (int q = 0; q < 16; ++q) {
                const int dq = q * 4;
                const f32x4 f   = *(const f32x4*)(fs + row * 64 + (dq ^ swz));
                const f32x4 iv4 = *(const f32x4*)(ivp + dq);
                xx = fmaf(f.x * iv4.x, f.x, xx);
                xx = fmaf(f.y * iv4.y, f.y, xx);
                xx = fmaf(f.z * iv4.z, f.z, xx);
                xx = fmaf(f.w * iv4.w, f.w, xx);
            }
            xxl[row] = xx;
        }
        {
            const float ln = *slnp;
            if (tid < C) slncc[tid] = ln + scc[tid];
            for (int e = tid; e < KRUN * C; e += 256) {
                const int k = e >> 5, c = e & 31;
                const float plr = PLR[c];
                sllp[e] = (float)(k + 1) * (plr + ln + scc[c]) - expf(plr) - lgam[k];
            }
        }
        __syncthreads();

        // =================== P2: cumsum pass2 -> csbf; csxx pass1 ============
        {
            float off = 0.f;
#pragma unroll
            for (int s2 = 0; s2 < 3; ++s2) off += (s2 < seg) ? red[s2 * 64 + col] : 0.f;
            float run = off;
#pragma unroll
            for (int q = 0; q < CR; ++q) {
                const int row = seg * CR + q;
                csbf[row * 64 + (((col >> 3) ^ (row & 7)) << 3) + (col & 7)] = f2bf(run);
                run += loc[q];
            }
            if (seg == 3)
                csbf[RTOT * 64 + (((col >> 3) ^ (RTOT & 7)) << 3) + (col & 7)] = f2bf(run);
        }
        if (tid < 8) {
            float r2 = 0.f;
            for (int q = 0; q < XSEG; ++q) {
                const int i = tid * XSEG + q;
                if (i < RTOT) { csxx[i] = r2; r2 += xxl[i]; }
            }
            red2[tid] = r2;
        }
        __syncthreads();

        // =================== P3: csxx finalize + MFMA ===================
        if (tid < ROWS) {
            const int r = tid;
            if (r == RTOT) {
                float t = 0.f;
#pragma unroll
                for (int s2 = 0; s2 < 8; ++s2) t += red2[s2];
                csxx[r] = t;
            } else {
                const int sg = r / XSEG;
                float o = 0.f;
#pragma unroll
                for (int s2 = 0; s2 < 8; ++s2) o += (s2 < sg) ? red2[s2] : 0.f;
                csxx[r] = csxx[r] + o;
            }
        }
        {
            const int l = tid & 63, wid = tid >> 6;
            bf16x8 bfr[2][2];
#pragma unroll
            for (int ct = 0; ct < 2; ++ct)
#pragma unroll
                for (int h = 0; h < 2; ++h) {
                    const int c  = ct * 16 + (l & 15);
                    const int k0 = h * 32 + (l >> 4) * 8;
                    bfr[ct][h] = *(const bf16x8*)(wmb + c * 72 + k0);
                }
            for (int j = wid; j < NT * 2; j += 4) {
                const int rt = j >> 1, ct = j & 1;
                const int arow = rt * 16 + (l & 15);
                const int kb = l >> 4;
                const bf16x8 a0 = *(const bf16x8*)(csbf + arow * 64 + ((kb ^ (arow & 7)) << 3));
                const bf16x8 a1 = *(const bf16x8*)(csbf + arow * 64 + (((4 + kb) ^ (arow & 7)) << 3));
                f32x4 acc = {0.f, 0.f, 0.f, 0.f};
                acc = __builtin_amdgcn_mfma_f32_16x16x32_bf16(a0, bfr[ct][0], acc, 0, 0, 0);
                acc = __builtin_amdgcn_mfma_f32_16x16x32_bf16(a1, bfr[ct][1], acc, 0, 0, 0);
                const int r0  = rt * 16 + (l >> 4) * 4;
                const int cc0 = ct * 16 + (l & 15);
#pragma unroll
                for (int reg = 0; reg < 4; ++reg) {
                    const int r = r0 + reg;
                    if (r < ROWS) S[r * 36 + cc0] = acc[reg];
                }
            }
        }
        __syncthreads();

        // =================== P4: span compute + stores ===================
        const int c4 = (tid & 7) << 2;
        const int tb = tid >> 3;                 // 0..31
        const int ja = tb + KT;
        const int jb = ja + 32;
        const int ta = t0 + tb;
        const int tbg = t0 + 32 + tb;

        const f32x4 ea  = *(const f32x4*)&S[(ja + 1) * 36 + c4];
        const f32x4 eb  = *(const f32x4*)&S[(jb + 1) * 36 + c4];
        const f32x4 ln4 = *(const f32x4*)&slncc[c4];
        const float xea = csxx[ja + 1];
        const float xeb = csxx[jb + 1];

        float* ob = out + ((size_t)(b * KRUN) * T + t0) * C + c4;
#pragma unroll
        for (int k = 0; k < KRUN; ++k) {
            const f32x4 lv = *(const f32x4*)&sllp[k * 32 + c4];
            const f32x4 sa = *(const f32x4*)&S[(ja - k) * 36 + c4];
            const f32x4 sb = *(const f32x4*)&S[(jb - k) * 36 + c4];
            const float dxa = xea - csxx[ja - k];
            const float dxb = xeb - csxx[jb - k];
            const f32x4 mk = BIG_NEG - (float)(k + 1) * ln4;
            f32x4 ra = ea - sa + (lv - 0.5f * dxa);
            f32x4 rb = eb - sb + (lv - 0.5f * dxb);
            if (ta < k) ra = mk + lv;
            if (tbg < k) rb = mk + lv;
            float* op = ob + (size_t)k * T * C;
            *(f32x4*)(op + tb * C) = ra;
            *(f32x4*)(op + (32 + tb) * C) = rb;
        }

    } else if (bid == 512) {
        // ---------------- transition log-softmax ----------------
        float* left  = smem;            // C*NF
        float* right = smem + 512;      // C*NF
        float* M     = smem + 1024;     // C*(C+1)
        float* lse   = smem + 2112;     // C
        for (int e = tid; e < C * NF; e += 256) {
            int cc = e >> 4, f = e & (NF - 1);
            float aL = 0.f, aR = 0.f;
            for (int d = 0; d < D; ++d) {
                float p = P[d * NF + f];
                aL = fmaf(TL[cc * D + d], p, aL);
                aR = fmaf(TR[cc * D + d], p, aR);
            }
            left[cc * NF + f] = aL;
            right[cc * NF + f] = aR;
        }
        __syncthreads();
        for (int e = tid; e < C * C; e += 256) {
            int i = e >> 5, jj = e & 31;
            float acc = 0.f;
            for (int f = 0; f < NF; ++f)
                acc = fmaf(right[i * NF + f], left[jj * NF + f], acc);
            M[i * 33 + jj] = acc;
        }
        __syncthreads();
        if (tid < C) {
            float mx = -INFINITY;
            for (int i = 0; i < C; ++i) mx = fmaxf(mx, M[i * 33 + tid]);
            float s = 0.f;
            for (int i = 0; i < C; ++i) s += expf(M[i * 33 + tid] - mx);
            lse[tid] = logf(s) + mx;
        }
        __syncthreads();
        for (int e = tid; e < C * C; e += 256)
            out_trans[e] = M[(e >> 5) * 33 + (e & 31)] - lse[e & 31];

    } else {
        // ---------------- init_lp ----------------
        if (tid < 32) {
            float vv = LOGITS[tid];
            float mx = vv;
#pragma unroll
            for (int off = 1; off < 32; off <<= 1)
                mx = fmaxf(mx, __shfl_xor(mx, off, 64));
            float s = expf(vv - mx);
#pragma unroll
            for (int off = 1; off < 32; off <<= 1) s += __shfl_xor(s, off, 64);
            out_init[tid] = vv - mx - logf(s);
        }
    }
}

// ---------------------------------------------------------------------------
extern "C" void kernel_launch(void* const* d_in, const int* in_sizes, int n_in,
                              void* d_out, int out_size, void* d_ws, size_t ws_size,
                              hipStream_t stream) {
    const float* feat   = (const float*)d_in[0];
    const float* P      = (const float*)d_in[1];
    const float* TL     = (const float*)d_in[2];
    const float* TR     = (const float*)d_in[3];
    const float* MEANS  = (const float*)d_in[4];
    const float* STDV   = (const float*)d_in[5];
    const float* PLR    = (const float*)d_in[6];
    const float* LOGITS = (const float*)d_in[7];

    const int K = (out_size - (C * C + C)) / (B * T * C);

    float* out       = (float*)d_out;
    float* out_trans = out + (size_t)B * K * T * C;
    float* out_init  = out_trans + C * C;

    if (K == 20) {
        megakernel<20, true><<<514, 256, 0, stream>>>(
            feat, P, TL, TR, STDV, MEANS, PLR, LOGITS,
            out, out_trans, out_init, K);
    } else if (K == 16) {
        megakernel<16, true><<<514, 256, 0, stream>>>(
            feat, P, TL, TR, STDV, MEANS, PLR, LOGITS,
            out, out_trans, out_init, K);
    } else if (K == 24) {
        megakernel<24, true><<<514, 256, 0, stream>>>(
            feat, P, TL, TR, STDV, MEANS, PLR, LOGITS,
            out, out_trans, out_init, K);
    } else {
        megakernel<32, false><<<514, 256, 0, stream>>>(
            feat, P, TL, TR, STDV, MEANS, PLR, LOGITS,
            out, out_trans, out_init, K);
    }
}

// Round 16
// 25.586 us; speedup vs baseline: 1.2158x; 1.0061x over previous
//
#include <hip/hip_runtime.h>
#include <math.h>

#define BIG_NEG (-1.0e9f)

constexpr int B = 16, T = 2048, D = 64, C = 32, NF = 16;

typedef float f32x4 __attribute__((ext_vector_type(4)));
using bf16x8 = __attribute__((ext_vector_type(8))) short;

__device__ inline ushort f2bf(float x) {
    union { float f; unsigned u; } cv; cv.f = x;
    unsigned u = cv.u;
    u += 0x7FFF + ((u >> 16) & 1);          // RNE
    return (ushort)(u >> 16);
}

// ---------------------------------------------------------------------------
// megakernel v5: v3 numerics, 512 threads/block -> 16 waves/CU in the store
// phase (store-TLP). Blocks 0..511 work; 512 = trans; 513 = init.
// ---------------------------------------------------------------------------
template<int KT, bool EXACT>
__global__ __launch_bounds__(512) void megakernel(
    const float* __restrict__ feat,    // (B,T,D)
    const float* __restrict__ P,       // (D,NF)
    const float* __restrict__ TL,      // (C,D)
    const float* __restrict__ TR,      // (C,D)
    const float* __restrict__ STD,     // (D,)
    const float* __restrict__ MEANS,   // (C,D)
    const float* __restrict__ PLR,     // (C,)
    const float* __restrict__ LOGITS,  // (C,)
    float* __restrict__ out,           // (B,K,T,C)
    float* __restrict__ out_trans,     // (C,C)
    float* __restrict__ out_init,      // (C,)
    int Krt)
{
    constexpr int RTOT = 64 + KT;           // em rows (halo + chunk)
    constexpr int ROWS = RTOT + 1;          // prefix rows
    constexpr int NT   = (ROWS + 15) / 16;  // 16-row MFMA tiles
    constexpr int CR   = (RTOT + 7) / 8;    // cumsum rows per thread (8 segs)
    constexpr int XSEG = (RTOT + 7) / 8;    // csxx segment length

    // --- smem carve (f32 units) ---
    constexpr int OFF_FS   = 0;                          // RTOT*64 (S overlays)
    constexpr int OFF_CSBF = OFF_FS + RTOT * 64;         // NT*16*32 (ushort buf)
    constexpr int OFF_WMBF = OFF_CSBF + NT * 16 * 32;    // 1152 (32*72 ushort)
    constexpr int OFF_XX   = OFF_WMBF + 1152;            // RTOT
    constexpr int OFF_CSXX = OFF_XX + RTOT;              // ROWS
    constexpr int OFF_RED  = (OFF_CSXX + ROWS + 3) & ~3; // 512
    constexpr int OFF_RED2 = OFF_RED + 512;              // 8
    constexpr int OFF_LLP  = OFF_RED2 + 8;               // KT*32
    constexpr int OFF_LNCC = OFF_LLP + KT * 32;          // 32
    constexpr int OFF_LGAM = OFF_LNCC + 32;              // 32
    constexpr int OFF_SCC  = OFF_LGAM + 32;              // 32
    constexpr int OFF_SLN  = OFF_SCC + 32;               // 4
    constexpr int OFF_IV   = OFF_SLN + 4;                // 64
    constexpr int SMEM_F32 = OFF_IV + 64;
    __shared__ float smem[SMEM_F32];

    float*  fs    = smem + OFF_FS;
    float*  S     = smem + OFF_FS;          // overlay (fs dead after P2)
    ushort* csbf  = (ushort*)(smem + OFF_CSBF);
    ushort* wmb   = (ushort*)(smem + OFF_WMBF);
    float*  xxl   = smem + OFF_XX;
    float*  csxx  = smem + OFF_CSXX;
    float*  red   = smem + OFF_RED;
    float*  red2  = smem + OFF_RED2;
    float*  sllp  = smem + OFF_LLP;
    float*  slncc = smem + OFF_LNCC;
    float*  lgam  = smem + OFF_LGAM;
    float*  scc   = smem + OFF_SCC;
    float*  slnp  = smem + OFF_SLN;
    float*  ivp   = smem + OFF_IV;

    const int bid = blockIdx.x;
    const int tid = threadIdx.x;
    const int KRUN = EXACT ? KT : Krt;

    if (bid < 512) {
        const int b  = bid & 15;            // XCD = b%8
        const int t0 = (bid >> 4) << 6;     // chunk * 64

        // =================== P0: staging ===================
        const float* fb = feat + (size_t)b * T * D;
        constexpr int NF4 = RTOT * 16;
#pragma unroll
        for (int it = 0; it < (NF4 + 511) / 512; ++it) {
            const int idx4 = tid + it * 512;
            if (idx4 < NF4) {
                const int fi  = idx4 * 4;
                const int row = fi >> 6;
                const int col = fi & 63;
                const int t   = t0 - KT + row;
                f32x4 v = {0.f, 0.f, 0.f, 0.f};
                if (t >= 0) v = *(const f32x4*)(fb + (size_t)t * D + col);
                const int cswz = col ^ (((row >> 2) & 7) << 2);
                *(f32x4*)(fs + row * 64 + cswz) = v;
            }
        }
        // wm bf16 [c][72] — 2048 floats, one ushort4 per thread
        {
            const int idx = tid * 4;
            const int c = idx >> 6, d = idx & 63;
            const f32x4 m = *(const f32x4*)(MEANS + idx);
            const f32x4 s = *(const f32x4*)(STD + d);
            ushort4 u;
            u.x = f2bf(m.x / (s.x * s.x));
            u.y = f2bf(m.y / (s.y * s.y));
            u.z = f2bf(m.z / (s.z * s.z));
            u.w = f2bf(m.w / (s.w * s.w));
            *(ushort4*)(wmb + c * 72 + d) = u;
        }
        if (tid < 16) {
            const f32x4 s = *(const f32x4*)(STD + tid * 4);
            f32x4 v = {1.f / (s.x * s.x), 1.f / (s.y * s.y),
                       1.f / (s.z * s.z), 1.f / (s.w * s.w)};
            *(f32x4*)(ivp + tid * 4) = v;
        }
        // tables
        if (tid < 32) {
            float x = (tid >= 1) ? logf((float)(tid + 1)) : 0.f;
#pragma unroll
            for (int off = 1; off < 32; off <<= 1) {
                float vv = __shfl_up(x, off, 64);
                if (tid >= off) x += vv;
            }
            lgam[tid] = x;                 // lgamma(k+2)
        } else if (tid >= 64 && tid < 128) {
            const int l = tid - 64;
            float lg = logf(STD[l]);
#pragma unroll
            for (int off = 1; off < 64; off <<= 1) lg += __shfl_xor(lg, off, 64);
            if (l == 0) *slnp = -lg - 58.81206612510332f;
        } else if (tid >= 192 && tid < 224) {
            const int c = tid - 192;
            float acc = 0.f;
#pragma unroll
            for (int dq = 0; dq < 64; dq += 4) {
                const f32x4 m = *(const f32x4*)(MEANS + c * 64 + dq);
                const f32x4 s = *(const f32x4*)(STD + dq);
                acc += (m.x * m.x) / (s.x * s.x) + (m.y * m.y) / (s.y * s.y)
                     + (m.z * m.z) / (s.z * s.z) + (m.w * m.w) / (s.w * s.w);
            }
            scc[c] = -0.5f * acc;
        }
        __syncthreads();

        // =================== P1: cumsum pass1 + xx + sllp ===================
        const int col = tid & 63, seg = tid >> 6;   // 8 segments of CR rows
        float loc[CR];
        {
            float runp = 0.f;
#pragma unroll
            for (int q = 0; q < CR; ++q) {
                const int row = seg * CR + q;
                float v = 0.f;
                if (row < RTOT)
                    v = fs[row * 64 + (col ^ (((row >> 2) & 7) << 2))];
                loc[q] = v;
                runp += v;
            }
            red[seg * 64 + col] = runp;
        }
        if (tid < RTOT) {
            const int row = tid;
            const int swz = ((row >> 2) & 7) << 2;
            float xx = 0.f;
#pragma unroll
            for (int q = 0; q < 16; ++q) {
                const int dq = q * 4;
                const f32x4 f   = *(const f32x4*)(fs + row * 64 + (dq ^ swz));
                const f32x4 iv4 = *(const f32x4*)(ivp + dq);
                xx = fmaf(f.x * iv4.x, f.x, xx);
                xx = fmaf(f.y * iv4.y, f.y, xx);
                xx = fmaf(f.z * iv4.z, f.z, xx);
                xx = fmaf(f.w * iv4.w, f.w, xx);
            }
            xxl[row] = xx;
        }
        {
            const float ln = *slnp;
            if (tid < C) slncc[tid] = ln + scc[tid];
            for (int e = tid; e < KRUN * C; e += 512) {
                const int k = e >> 5, c = e & 31;
                const float plr = PLR[c];
                sllp[e] = (float)(k + 1) * (plr + ln + scc[c]) - expf(plr) - lgam[k];
            }
        }
        __syncthreads();

        // =================== P2: cumsum pass2 -> csbf; csxx pass1 ============
        {
            float off = 0.f;
#pragma unroll
            for (int s2 = 0; s2 < 8; ++s2) off += (s2 < seg) ? red[s2 * 64 + col] : 0.f;
            float run = off;
#pragma unroll
            for (int q = 0; q < CR; ++q) {
                const int row = seg * CR + q;
                if (row < RTOT) {
                    csbf[row * 64 + (((col >> 3) ^ (row & 7)) << 3) + (col & 7)] = f2bf(run);
                    run += loc[q];
                }
            }
            if (seg == 7)
                csbf[RTOT * 64 + (((col >> 3) ^ (RTOT & 7)) << 3) + (col & 7)] = f2bf(run);
        }
        if (tid < 8) {
            float r2 = 0.f;
            for (int q = 0; q < XSEG; ++q) {
                const int i = tid * XSEG + q;
                if (i < RTOT) { csxx[i] = r2; r2 += xxl[i]; }
            }
            red2[tid] = r2;
        }
        __syncthreads();

        // =================== P3: csxx finalize + MFMA ===================
        if (tid < ROWS) {
            const int r = tid;
            if (r == RTOT) {
                float t = 0.f;
#pragma unroll
                for (int s2 = 0; s2 < 8; ++s2) t += red2[s2];
                csxx[r] = t;
            } else {
                const int sg = r / XSEG;
                float o = 0.f;
#pragma unroll
                for (int s2 = 0; s2 < 8; ++s2) o += (s2 < sg) ? red2[s2] : 0.f;
                csxx[r] = csxx[r] + o;
            }
        }
        {
            const int l = tid & 63, wid = tid >> 6;  // 8 waves
            bf16x8 bfr[2][2];
#pragma unroll
            for (int ct = 0; ct < 2; ++ct)
#pragma unroll
                for (int h = 0; h < 2; ++h) {
                    const int c  = ct * 16 + (l & 15);
                    const int k0 = h * 32 + (l >> 4) * 8;
                    bfr[ct][h] = *(const bf16x8*)(wmb + c * 72 + k0);
                }
            for (int j = wid; j < NT * 2; j += 8) {
                const int rt = j >> 1, ct = j & 1;
                const int arow = rt * 16 + (l & 15);
                const int kb = l >> 4;
                const bf16x8 a0 = *(const bf16x8*)(csbf + arow * 64 + ((kb ^ (arow & 7)) << 3));
                const bf16x8 a1 = *(const bf16x8*)(csbf + arow * 64 + (((4 + kb) ^ (arow & 7)) << 3));
                f32x4 acc = {0.f, 0.f, 0.f, 0.f};
                acc = __builtin_amdgcn_mfma_f32_16x16x32_bf16(a0, bfr[ct][0], acc, 0, 0, 0);
                acc = __builtin_amdgcn_mfma_f32_16x16x32_bf16(a1, bfr[ct][1], acc, 0, 0, 0);
                const int r0  = rt * 16 + (l >> 4) * 4;
                const int cc0 = ct * 16 + (l & 15);
#pragma unroll
                for (int reg = 0; reg < 4; ++reg) {
                    const int r = r0 + reg;
                    if (r < ROWS) S[r * 36 + cc0] = acc[reg];
                }
            }
        }
        __syncthreads();

        // =================== P4: span compute + stores (1 row/thread) ========
        const int c4 = (tid & 7) << 2;
        const int tb = tid >> 3;                 // 0..63
        const int ja = tb + KT;
        const int ta = t0 + tb;

        const f32x4 ea  = *(const f32x4*)&S[(ja + 1) * 36 + c4];
        const f32x4 ln4 = *(const f32x4*)&slncc[c4];
        const float xea = csxx[ja + 1];

        float* ob = out + ((size_t)(b * KRUN) * T + t0) * C + c4;
#pragma unroll
        for (int k = 0; k < KRUN; ++k) {
            const f32x4 lv = *(const f32x4*)&sllp[k * 32 + c4];
            const f32x4 sa = *(const f32x4*)&S[(ja - k) * 36 + c4];
            const float dxa = xea - csxx[ja - k];
            const f32x4 mk = BIG_NEG - (float)(k + 1) * ln4;
            f32x4 ra = ea - sa + (lv - 0.5f * dxa);
            if (ta < k) ra = mk + lv;
            *(f32x4*)(ob + (size_t)k * T * C + tb * C) = ra;
        }

    } else if (bid == 512) {
        // ---------------- transition log-softmax ----------------
        float* left  = smem;            // C*NF
        float* right = smem + 512;      // C*NF
        float* M     = smem + 1024;     // C*(C+1)
        float* lse   = smem + 2112;     // C
        for (int e = tid; e < C * NF; e += 512) {
            int cc = e >> 4, f = e & (NF - 1);
            float aL = 0.f, aR = 0.f;
            for (int d = 0; d < D; ++d) {
                float p = P[d * NF + f];
                aL = fmaf(TL[cc * D + d], p, aL);
                aR = fmaf(TR[cc * D + d], p, aR);
            }
            left[cc * NF + f] = aL;
            right[cc * NF + f] = aR;
        }
        __syncthreads();
        for (int e = tid; e < C * C; e += 512) {
            int i = e >> 5, jj = e & 31;
            float acc = 0.f;
            for (int f = 0; f < NF; ++f)
                acc = fmaf(right[i * NF + f], left[jj * NF + f], acc);
            M[i * 33 + jj] = acc;
        }
        __syncthreads();
        if (tid < C) {
            float mx = -INFINITY;
            for (int i = 0; i < C; ++i) mx = fmaxf(mx, M[i * 33 + tid]);
            float s = 0.f;
            for (int i = 0; i < C; ++i) s += expf(M[i * 33 + tid] - mx);
            lse[tid] = logf(s) + mx;
        }
        __syncthreads();
        for (int e = tid; e < C * C; e += 512)
            out_trans[e] = M[(e >> 5) * 33 + (e & 31)] - lse[e & 31];

    } else {
        // ---------------- init_lp ----------------
        if (tid < 32) {
            float vv = LOGITS[tid];
            float mx = vv;
#pragma unroll
            for (int off = 1; off < 32; off <<= 1)
                mx = fmaxf(mx, __shfl_xor(mx, off, 64));
            float s = expf(vv - mx);
#pragma unroll
            for (int off = 1; off < 32; off <<= 1) s += __shfl_xor(s, off, 64);
            out_init[tid] = vv - mx - logf(s);
        }
    }
}

// ---------------------------------------------------------------------------
extern "C" void kernel_launch(void* const* d_in, const int* in_sizes, int n_in,
                              void* d_out, int out_size, void* d_ws, size_t ws_size,
                              hipStream_t stream) {
    const float* feat   = (const float*)d_in[0];
    const float* P      = (const float*)d_in[1];
    const float* TL     = (const float*)d_in[2];
    const float* TR     = (const float*)d_in[3];
    const float* MEANS  = (const float*)d_in[4];
    const float* STDV   = (const float*)d_in[5];
    const float* PLR    = (const float*)d_in[6];
    const float* LOGITS = (const float*)d_in[7];

    const int K = (out_size - (C * C + C)) / (B * T * C);

    float* out       = (float*)d_out;
    float* out_trans = out + (size_t)B * K * T * C;
    float* out_init  = out_trans + C * C;

    if (K == 20) {
        megakernel<20, true><<<514, 512, 0, stream>>>(
            feat, P, TL, TR, STDV, MEANS, PLR, LOGITS,
            out, out_trans, out_init, K);
    } else if (K == 16) {
        megakernel<16, true><<<514, 512, 0, stream>>>(
            feat, P, TL, TR, STDV, MEANS, PLR, LOGITS,
            out, out_trans, out_init, K);
    } else if (K == 24) {
        megakernel<24, true><<<514, 512, 0, stream>>>(
            feat, P, TL, TR, STDV, MEANS, PLR, LOGITS,
            out, out_trans, out_init, K);
    } else {
        megakernel<32, false><<<514, 512, 0, stream>>>(
            feat, P, TL, TR, STDV, MEANS, PLR, LOGITS,
            out, out_trans, out_init, K);
    }
}

// Round 17
// 25.330 us; speedup vs baseline: 1.2281x; 1.0101x over previous
//
#include <hip/hip_runtime.h>
#include <math.h>

#define BIG_NEG (-1.0e9f)

constexpr int B = 16, T = 2048, D = 64, C = 32, NF = 16;

typedef float f32x4 __attribute__((ext_vector_type(4)));
using bf16x8 = __attribute__((ext_vector_type(8))) short;

__device__ inline ushort f2bf(float x) {
    union { float f; unsigned u; } cv; cv.f = x;
    unsigned u = cv.u;
    u += 0x7FFF + ((u >> 16) & 1);          // RNE
    return (ushort)(u >> 16);
}

// ---------------------------------------------------------------------------
// megakernel v6: chunk 32, 1024 work blocks (4/CU), enforced stagger so the
// HBM write stream starts after ONE small block's compute (~2.5us) instead of
// after the whole CU's compute (~8us). MFMA emission path (v3 numerics).
//  blocks 0..1023 : (b, t-chunk of 32)
//  block  1024    : transition log-softmax
//  block  1025    : init_lp
// ---------------------------------------------------------------------------
template<int KT, bool EXACT>
__global__ __launch_bounds__(256) void megakernel(
    const float* __restrict__ feat,    // (B,T,D)
    const float* __restrict__ P,       // (D,NF)
    const float* __restrict__ TL,      // (C,D)
    const float* __restrict__ TR,      // (C,D)
    const float* __restrict__ STD,     // (D,)
    const float* __restrict__ MEANS,   // (C,D)
    const float* __restrict__ PLR,     // (C,)
    const float* __restrict__ LOGITS,  // (C,)
    float* __restrict__ out,           // (B,K,T,C)
    float* __restrict__ out_trans,     // (C,C)
    float* __restrict__ out_init,      // (C,)
    int Krt)
{
    constexpr int CHUNK = 32;
    constexpr int RTOT = CHUNK + KT;        // em rows (halo + chunk)
    constexpr int ROWS = RTOT + 1;          // prefix rows
    constexpr int NT   = (ROWS + 15) / 16;  // 16-row MFMA tiles
    constexpr int CR   = RTOT / 4;          // cumsum rows per thread (4 segs)
    constexpr int XSEG = (RTOT + 7) / 8;    // csxx segment length

    // --- smem carve (f32 units) ---
    constexpr int OFF_FS   = 0;                          // RTOT*64 (S overlays)
    constexpr int OFF_CSBF = OFF_FS + RTOT * 64;         // NT*16*32 (ushort buf)
    constexpr int OFF_WMBF = OFF_CSBF + NT * 16 * 32;    // 1152 (32*72 ushort)
    constexpr int OFF_XX   = OFF_WMBF + 1152;            // RTOT
    constexpr int OFF_CSXX = OFF_XX + RTOT;              // ROWS
    constexpr int OFF_RED  = (OFF_CSXX + ROWS + 3) & ~3; // 256
    constexpr int OFF_RED2 = OFF_RED + 256;              // 8
    constexpr int OFF_LLP  = OFF_RED2 + 8;               // KT*32
    constexpr int OFF_LNCC = OFF_LLP + KT * 32;          // 32
    constexpr int OFF_LGAM = OFF_LNCC + 32;              // 32
    constexpr int OFF_SCC  = OFF_LGAM + 32;              // 32
    constexpr int OFF_SLN  = OFF_SCC + 32;               // 4
    constexpr int OFF_IV   = OFF_SLN + 4;                // 64
    constexpr int SMEM_F32 = OFF_IV + 64;
    __shared__ float smem[SMEM_F32];

    float*  fs    = smem + OFF_FS;
    float*  S     = smem + OFF_FS;          // overlay (fs dead after P2)
    ushort* csbf  = (ushort*)(smem + OFF_CSBF);
    ushort* wmb   = (ushort*)(smem + OFF_WMBF);
    float*  xxl   = smem + OFF_XX;
    float*  csxx  = smem + OFF_CSXX;
    float*  red   = smem + OFF_RED;
    float*  red2  = smem + OFF_RED2;
    float*  sllp  = smem + OFF_LLP;
    float*  slncc = smem + OFF_LNCC;
    float*  lgam  = smem + OFF_LGAM;
    float*  scc   = smem + OFF_SCC;
    float*  slnp  = smem + OFF_SLN;
    float*  ivp   = smem + OFF_IV;

    const int bid = blockIdx.x;
    const int tid = threadIdx.x;
    const int KRUN = EXACT ? KT : Krt;

    if (bid < 1024) {
        // ---- enforced stagger: dispatch round r sleeps r * ~2.1us so the
        // CU's HBM stream starts after one SMALL block's compute ----
        {
            const int r = bid >> 8;          // 0..3, one per co-resident slot
            for (int i = 0; i < r; ++i) __builtin_amdgcn_s_sleep(80);
        }

        const int b  = bid & 15;            // XCD = b%8
        const int t0 = (bid >> 4) << 5;     // chunk * 32

        // =================== P0: staging ===================
        const float* fb = feat + (size_t)b * T * D;
        constexpr int NF4 = RTOT * 16;
#pragma unroll
        for (int it = 0; it < (NF4 + 255) / 256; ++it) {
            const int idx4 = tid + it * 256;
            if (idx4 < NF4) {
                const int fi  = idx4 * 4;
                const int row = fi >> 6;
                const int col = fi & 63;
                const int t   = t0 - KT + row;
                f32x4 v = {0.f, 0.f, 0.f, 0.f};
                if (t >= 0) v = *(const f32x4*)(fb + (size_t)t * D + col);
                const int cswz = col ^ (((row >> 2) & 7) << 2);
                *(f32x4*)(fs + row * 64 + cswz) = v;
            }
        }
        // wm bf16 [c][72]
#pragma unroll
        for (int it = 0; it < 2; ++it) {
            const int idx = (tid + it * 256) * 4;
            const int c = idx >> 6, d = idx & 63;
            const f32x4 m = *(const f32x4*)(MEANS + idx);
            const f32x4 s = *(const f32x4*)(STD + d);
            ushort4 u;
            u.x = f2bf(m.x / (s.x * s.x));
            u.y = f2bf(m.y / (s.y * s.y));
            u.z = f2bf(m.z / (s.z * s.z));
            u.w = f2bf(m.w / (s.w * s.w));
            *(ushort4*)(wmb + c * 72 + d) = u;
        }
        if (tid < 16) {
            const f32x4 s = *(const f32x4*)(STD + tid * 4);
            f32x4 v = {1.f / (s.x * s.x), 1.f / (s.y * s.y),
                       1.f / (s.z * s.z), 1.f / (s.w * s.w)};
            *(f32x4*)(ivp + tid * 4) = v;
        }
        // tables
        if (tid < 32) {
            float x = (tid >= 1) ? logf((float)(tid + 1)) : 0.f;
#pragma unroll
            for (int off = 1; off < 32; off <<= 1) {
                float vv = __shfl_up(x, off, 64);
                if (tid >= off) x += vv;
            }
            lgam[tid] = x;                 // lgamma(k+2)
        } else if (tid >= 64 && tid < 128) {
            const int l = tid - 64;
            float lg = logf(STD[l]);
#pragma unroll
            for (int off = 1; off < 64; off <<= 1) lg += __shfl_xor(lg, off, 64);
            if (l == 0) *slnp = -lg - 58.81206612510332f;
        } else if (tid >= 192 && tid < 224) {
            const int c = tid - 192;
            float acc = 0.f;
#pragma unroll
            for (int dq = 0; dq < 64; dq += 4) {
                const f32x4 m = *(const f32x4*)(MEANS + c * 64 + dq);
                const f32x4 s = *(const f32x4*)(STD + dq);
                acc += (m.x * m.x) / (s.x * s.x) + (m.y * m.y) / (s.y * s.y)
                     + (m.z * m.z) / (s.z * s.z) + (m.w * m.w) / (s.w * s.w);
            }
            scc[c] = -0.5f * acc;
        }
        __syncthreads();

        // =================== P1: cumsum pass1 + xx + sllp ===================
        const int col = tid & 63, seg = tid >> 6;   // 4 segments of CR rows
        float loc[CR];
        {
            float runp = 0.f;
#pragma unroll
            for (int q = 0; q < CR; ++q) {
                const int row = seg * CR + q;
                const float v = fs[row * 64 + (col ^ (((row >> 2) & 7) << 2))];
                loc[q] = v;
                runp += v;
            }
            red[seg * 64 + col] = runp;
        }
        if (tid < RTOT) {
            const int row = tid;
            const int swz = ((row >> 2) & 7) << 2;
            float xx = 0.f;
#pragma unroll
            for (int q = 0; q < 16; ++q) {
                const int dq = q * 4;
                const f32x4 f   = *(const f32x4*)(fs + row * 64 + (dq ^ swz));
                const f32x4 iv4 = *(const f32x4*)(ivp + dq);
                xx = fmaf(f.x * iv4.x, f.x, xx);
                xx = fmaf(f.y * iv4.y, f.y, xx);
                xx = fmaf(f.z * iv4.z, f.z, xx);
                xx = fmaf(f.w * iv4.w, f.w, xx);
            }
            xxl[row] = xx;
        }
        {
            const float ln = *slnp;
            if (tid < C) slncc[tid] = ln + scc[tid];
            for (int e = tid; e < KRUN * C; e += 256) {
                const int k = e >> 5, c = e & 31;
                const float plr = PLR[c];
                sllp[e] = (float)(k + 1) * (plr + ln + scc[c]) - expf(plr) - lgam[k];
            }
        }
        __syncthreads();

        // =================== P2: cumsum pass2 -> csbf; csxx pass1 ============
        {
            float off = 0.f;
#pragma unroll
            for (int s2 = 0; s2 < 3; ++s2) off += (s2 < seg) ? red[s2 * 64 + col] : 0.f;
            float run = off;
#pragma unroll
            for (int q = 0; q < CR; ++q) {
                const int row = seg * CR + q;
                csbf[row * 64 + (((col >> 3) ^ (row & 7)) << 3) + (col & 7)] = f2bf(run);
                run += loc[q];
            }
            if (seg == 3)
                csbf[RTOT * 64 + (((col >> 3) ^ (RTOT & 7)) << 3) + (col & 7)] = f2bf(run);
        }
        if (tid < 8) {
            float r2 = 0.f;
            for (int q = 0; q < XSEG; ++q) {
                const int i = tid * XSEG + q;
                if (i < RTOT) { csxx[i] = r2; r2 += xxl[i]; }
            }
            red2[tid] = r2;
        }
        __syncthreads();

        // =================== P3: csxx finalize + MFMA ===================
        if (tid < ROWS) {
            const int r = tid;
            if (r == RTOT) {
                float t = 0.f;
#pragma unroll
                for (int s2 = 0; s2 < 8; ++s2) t += red2[s2];
                csxx[r] = t;
            } else {
                const int sg = r / XSEG;
                float o = 0.f;
#pragma unroll
                for (int s2 = 0; s2 < 8; ++s2) o += (s2 < sg) ? red2[s2] : 0.f;
                csxx[r] = csxx[r] + o;
            }
        }
        {
            const int l = tid & 63, wid = tid >> 6;  // 4 waves
            bf16x8 bfr[2][2];
#pragma unroll
            for (int ct = 0; ct < 2; ++ct)
#pragma unroll
                for (int h = 0; h < 2; ++h) {
                    const int c  = ct * 16 + (l & 15);
                    const int k0 = h * 32 + (l >> 4) * 8;
                    bfr[ct][h] = *(const bf16x8*)(wmb + c * 72 + k0);
                }
            for (int j = wid; j < NT * 2; j += 4) {
                const int rt = j >> 1, ct = j & 1;
                const int arow = rt * 16 + (l & 15);
                const int kb = l >> 4;
                const bf16x8 a0 = *(const bf16x8*)(csbf + arow * 64 + ((kb ^ (arow & 7)) << 3));
                const bf16x8 a1 = *(const bf16x8*)(csbf + arow * 64 + (((4 + kb) ^ (arow & 7)) << 3));
                f32x4 acc = {0.f, 0.f, 0.f, 0.f};
                acc = __builtin_amdgcn_mfma_f32_16x16x32_bf16(a0, bfr[ct][0], acc, 0, 0, 0);
                acc = __builtin_amdgcn_mfma_f32_16x16x32_bf16(a1, bfr[ct][1], acc, 0, 0, 0);
                const int r0  = rt * 16 + (l >> 4) * 4;
                const int cc0 = ct * 16 + (l & 15);
#pragma unroll
                for (int reg = 0; reg < 4; ++reg) {
                    const int r = r0 + reg;
                    if (r < ROWS) S[r * 36 + cc0] = acc[reg];
                }
            }
        }
        __syncthreads();

        // =================== P4: span compute + stores (1 row/thread) ========
        const int c4 = (tid & 7) << 2;
        const int tb = tid >> 3;                 // 0..31
        const int ja = tb + KT;
        const int ta = t0 + tb;

        const f32x4 ea  = *(const f32x4*)&S[(ja + 1) * 36 + c4];
        const f32x4 ln4 = *(const f32x4*)&slncc[c4];
        const float xea = csxx[ja + 1];

        float* ob = out + ((size_t)(b * KRUN) * T + t0) * C + c4;
#pragma unroll
        for (int k = 0; k < KRUN; ++k) {
            const f32x4 lv = *(const f32x4*)&sllp[k * 32 + c4];
            const f32x4 sa = *(const f32x4*)&S[(ja - k) * 36 + c4];
            const float dxa = xea - csxx[ja - k];
            const f32x4 mk = BIG_NEG - (float)(k + 1) * ln4;
            f32x4 ra = ea - sa + (lv - 0.5f * dxa);
            if (ta < k) ra = mk + lv;
            *(f32x4*)(ob + (size_t)k * T * C + tb * C) = ra;
        }

    } else if (bid == 1024) {
        // ---------------- transition log-softmax ----------------
        float* left  = smem;            // C*NF
        float* right = smem + 512;      // C*NF
        float* M     = smem + 1024;     // C*(C+1)
        float* lse   = smem + 2112;     // C
        for (int e = tid; e < C * NF; e += 256) {
            int cc = e >> 4, f = e & (NF - 1);
            float aL = 0.f, aR = 0.f;
            for (int d = 0; d < D; ++d) {
                float p = P[d * NF + f];
                aL = fmaf(TL[cc * D + d], p, aL);
                aR = fmaf(TR[cc * D + d], p, aR);
            }
            left[cc * NF + f] = aL;
            right[cc * NF + f] = aR;
        }
        __syncthreads();
        for (int e = tid; e < C * C; e += 256) {
            int i = e >> 5, jj = e & 31;
            float acc = 0.f;
            for (int f = 0; f < NF; ++f)
                acc = fmaf(right[i * NF + f], left[jj * NF + f], acc);
            M[i * 33 + jj] = acc;
        }
        __syncthreads();
        if (tid < C) {
            float mx = -INFINITY;
            for (int i = 0; i < C; ++i) mx = fmaxf(mx, M[i * 33 + tid]);
            float s = 0.f;
            for (int i = 0; i < C; ++i) s += expf(M[i * 33 + tid] - mx);
            lse[tid] = logf(s) + mx;
        }
        __syncthreads();
        for (int e = tid; e < C * C; e += 256)
            out_trans[e] = M[(e >> 5) * 33 + (e & 31)] - lse[e & 31];

    } else {
        // ---------------- init_lp ----------------
        if (tid < 32) {
            float vv = LOGITS[tid];
            float mx = vv;
#pragma unroll
            for (int off = 1; off < 32; off <<= 1)
                mx = fmaxf(mx, __shfl_xor(mx, off, 64));
            float s = expf(vv - mx);
#pragma unroll
            for (int off = 1; off < 32; off <<= 1) s += __shfl_xor(s, off, 64);
            out_init[tid] = vv - mx - logf(s);
        }
    }
}

// ---------------------------------------------------------------------------
extern "C" void kernel_launch(void* const* d_in, const int* in_sizes, int n_in,
                              void* d_out, int out_size, void* d_ws, size_t ws_size,
                              hipStream_t stream) {
    const float* feat   = (const float*)d_in[0];
    const float* P      = (const float*)d_in[1];
    const float* TL     = (const float*)d_in[2];
    const float* TR     = (const float*)d_in[3];
    const float* MEANS  = (const float*)d_in[4];
    const float* STDV   = (const float*)d_in[5];
    const float* PLR    = (const float*)d_in[6];
    const float* LOGITS = (const float*)d_in[7];

    const int K = (out_size - (C * C + C)) / (B * T * C);

    float* out       = (float*)d_out;
    float* out_trans = out + (size_t)B * K * T * C;
    float* out_init  = out_trans + C * C;

    if (K == 20) {
        megakernel<20, true><<<1026, 256, 0, stream>>>(
            feat, P, TL, TR, STDV, MEANS, PLR, LOGITS,
            out, out_trans, out_init, K);
    } else if (K == 16) {
        megakernel<16, true><<<1026, 256, 0, stream>>>(
            feat, P, TL, TR, STDV, MEANS, PLR, LOGITS,
            out, out_trans, out_init, K);
    } else if (K == 24) {
        megakernel<24, true><<<1026, 256, 0, stream>>>(
            feat, P, TL, TR, STDV, MEANS, PLR, LOGITS,
            out, out_trans, out_init, K);
    } else {
        megakernel<32, false><<<1026, 256, 0, stream>>>(
            feat, P, TL, TR, STDV, MEANS, PLR, LOGITS,
            out, out_trans, out_init, K);
    }
}